// Round 1
// baseline (152.171 us; speedup 1.0000x reference)
//
#include <hip/hip_runtime.h>
#include <hip/hip_bf16.h>

// Problem constants (from reference):
// B=2, N=6, D=120, H=32, W=88, C=128, Z=1, HO=128, WO=128
// HW = 32*88 = 2816, BN = 12, cells = B*Z*HO*WO = 32768, spatial = Z*HO*WO = 16384
#define HW_   2816
#define C_    128
#define BN_   12
#define SPAT_ 16384

// Transpose feat [BN, C, HW] -> featT [BN, HW, C] so per-point channel reads
// are contiguous (512B per point).
__global__ __launch_bounds__(256) void transpose_feat_k(const float* __restrict__ feat,
                                                        float* __restrict__ featT) {
    __shared__ float tile[32][33];
    const int bn  = blockIdx.z;
    const int hw0 = blockIdx.x * 32;
    const int c0  = blockIdx.y * 32;
    const int x = threadIdx.x;   // 0..31
    const int y = threadIdx.y;   // 0..7

    const float* src = feat + ((size_t)bn * C_ + c0) * HW_ + hw0;
    #pragma unroll
    for (int yy = y; yy < 32; yy += 8)
        tile[yy][x] = src[(size_t)yy * HW_ + x];     // coalesced along hw
    __syncthreads();
    float* dst = featT + ((size_t)bn * HW_ + hw0) * C_ + c0;
    #pragma unroll
    for (int yy = y; yy < 32; yy += 8)
        dst[(size_t)yy * C_ + x] = tile[x][yy];      // coalesced along c
}

// One wave per interval. Lane l accumulates channels (2l, 2l+1) as float2.
__global__ __launch_bounds__(256) void bevpool_main_k(const float* __restrict__ depth,
                                                      const float* __restrict__ featT,
                                                      const int* __restrict__ rd_arr,
                                                      const int* __restrict__ rf_arr,
                                                      const int* __restrict__ rb,
                                                      const int* __restrict__ istart,
                                                      const int* __restrict__ ilen,
                                                      float* __restrict__ out,
                                                      int n_intervals) {
    const int wave = (int)((blockIdx.x * blockDim.x + threadIdx.x) >> 6);
    const int lane = threadIdx.x & 63;
    if (wave >= n_intervals) return;

    const int start = istart[wave];
    const int len   = ilen[wave];
    const int cell  = rb[start];

    const float2* fT = (const float2*)featT;
    float ax = 0.f, ay = 0.f;
    const int end = start + len;
    for (int i = start; i < end; ++i) {
        const int   rdi = rd_arr[i];            // wave-uniform -> broadcast load
        const int   rfi = rf_arr[i];            // wave-uniform -> broadcast load
        const float d   = depth[rdi];           // wave-uniform -> broadcast load
        const float2 f  = fT[(size_t)rfi * (C_ / 2) + lane];  // coalesced 512B/wave
        ax = fmaf(d, f.x, ax);
        ay = fmaf(d, f.y, ay);
    }

    const int b  = cell >> 14;                  // cell / SPAT_
    const int sp = cell & (SPAT_ - 1);          // cell % SPAT_
    float* o = out + (size_t)b * (C_ * SPAT_) + sp;
    o[(size_t)(2 * lane)     * SPAT_] = ax;     // scattered 4B stores (profile later)
    o[(size_t)(2 * lane + 1) * SPAT_] = ay;
}

// Fallback (ws too small): read feat in original [BN, C, HW] layout directly.
__global__ __launch_bounds__(256) void bevpool_fallback_k(const float* __restrict__ depth,
                                                          const float* __restrict__ feat,
                                                          const int* __restrict__ rd_arr,
                                                          const int* __restrict__ rf_arr,
                                                          const int* __restrict__ rb,
                                                          const int* __restrict__ istart,
                                                          const int* __restrict__ ilen,
                                                          float* __restrict__ out,
                                                          int n_intervals) {
    const int wave = (int)((blockIdx.x * blockDim.x + threadIdx.x) >> 6);
    const int lane = threadIdx.x & 63;
    if (wave >= n_intervals) return;

    const int start = istart[wave];
    const int len   = ilen[wave];
    const int cell  = rb[start];

    float ax = 0.f, ay = 0.f;
    const int end = start + len;
    for (int i = start; i < end; ++i) {
        const int rfi = rf_arr[i];
        const int bn  = rfi / HW_;
        const int hw  = rfi - bn * HW_;
        const float d = depth[rd_arr[i]];
        const float* frow = feat + (size_t)bn * (C_ * HW_) + hw;
        ax = fmaf(d, frow[(size_t)(2 * lane)     * HW_], ax);
        ay = fmaf(d, frow[(size_t)(2 * lane + 1) * HW_], ay);
    }

    const int b  = cell >> 14;
    const int sp = cell & (SPAT_ - 1);
    float* o = out + (size_t)b * (C_ * SPAT_) + sp;
    o[(size_t)(2 * lane)     * SPAT_] = ax;
    o[(size_t)(2 * lane + 1) * SPAT_] = ay;
}

extern "C" void kernel_launch(void* const* d_in, const int* in_sizes, int n_in,
                              void* d_out, int out_size, void* d_ws, size_t ws_size,
                              hipStream_t stream) {
    const float* depth  = (const float*)d_in[0];
    const float* feat   = (const float*)d_in[1];
    const int*   rd     = (const int*)d_in[2];
    const int*   rf     = (const int*)d_in[3];
    const int*   rb     = (const int*)d_in[4];
    const int*   istart = (const int*)d_in[5];
    const int*   ilen   = (const int*)d_in[6];
    float*       out    = (float*)d_out;
    const int n_intervals = in_sizes[5];

    // Cells with no interval must be zero.
    hipMemsetAsync(d_out, 0, (size_t)out_size * sizeof(float), stream);

    const size_t featT_bytes = (size_t)BN_ * HW_ * C_ * sizeof(float);
    const int blocks = (n_intervals + 3) / 4;   // 4 waves per 256-thread block

    if (ws_size >= featT_bytes) {
        float* featT = (float*)d_ws;
        dim3 g(HW_ / 32, C_ / 32, BN_);
        dim3 b(32, 8);
        transpose_feat_k<<<g, b, 0, stream>>>(feat, featT);
        bevpool_main_k<<<blocks, 256, 0, stream>>>(depth, featT, rd, rf, rb,
                                                   istart, ilen, out, n_intervals);
    } else {
        bevpool_fallback_k<<<blocks, 256, 0, stream>>>(depth, feat, rd, rf, rb,
                                                       istart, ilen, out, n_intervals);
    }
}

// Round 2
// 85.498 us; speedup vs baseline: 1.7798x; 1.7798x over previous
//
#include <hip/hip_runtime.h>
#include <hip/hip_bf16.h>

// Problem constants (from reference):
// B=2, N=6, D=120, H=32, W=88, C=128, Z=1, HO=128, WO=128
#define HW_    2816
#define C_     128
#define BN_    12
#define SPAT_  16384
#define CELLS_ 32768

// ---------------------------------------------------------------------------
// feat [BN, C, HW] f32  ->  featT [BN, HW, C] bf16 (contiguous 256B per point)
// ---------------------------------------------------------------------------
__global__ __launch_bounds__(256) void transpose_feat_bf16_k(const float* __restrict__ feat,
                                                             __hip_bfloat16* __restrict__ featT) {
    __shared__ float tile[32][33];
    const int bn  = blockIdx.z;
    const int hw0 = blockIdx.x * 32;
    const int c0  = blockIdx.y * 32;
    const int x = threadIdx.x;   // 0..31
    const int y = threadIdx.y;   // 0..7

    const float* src = feat + ((size_t)bn * C_ + c0) * HW_ + hw0;
    #pragma unroll
    for (int yy = y; yy < 32; yy += 8)
        tile[yy][x] = src[(size_t)yy * HW_ + x];       // coalesced along hw
    __syncthreads();
    __hip_bfloat16* dst = featT + ((size_t)bn * HW_ + hw0) * C_ + c0;
    #pragma unroll
    for (int yy = y; yy < 32; yy += 8)
        dst[(size_t)yy * C_ + x] = __float2bfloat16(tile[x][yy]);  // coalesced along c
}

// ---------------------------------------------------------------------------
// Main: one wave per interval. Two 32-lane halves each own alternating points
// (4 channels/lane as bf16x4 = one uint2 load), hand-unrolled x2 so the wave
// keeps 4 independent gather chains in flight. Halves combined via shfl_down.
// COAL=true  -> store float4 to cellbuf[cell][c] (coalesced 512B)
// COAL=false -> scattered stores straight to out [b,c,sp]
// ---------------------------------------------------------------------------
template<bool COAL>
__global__ __launch_bounds__(256) void bevpool_main_bf16_k(const float* __restrict__ depth,
                                                           const uint2* __restrict__ featT,
                                                           const int* __restrict__ rd_arr,
                                                           const int* __restrict__ rf_arr,
                                                           const int* __restrict__ rb,
                                                           const int* __restrict__ istart,
                                                           const int* __restrict__ ilen,
                                                           float* __restrict__ dst,
                                                           int n_intervals) {
    const int wave = (int)((blockIdx.x * blockDim.x + threadIdx.x) >> 6);
    if (wave >= n_intervals) return;
    const int lane = threadIdx.x & 63;
    const int half = lane >> 5;     // 0 or 1: which point stream this half-wave owns
    const int sl   = lane & 31;     // channel group: channels 4*sl .. 4*sl+3

    const int start = istart[wave];
    const int end   = start + ilen[wave];
    const int cell  = rb[start];

    float a0 = 0.f, a1 = 0.f, a2 = 0.f, a3 = 0.f;
    for (int i = start + half; i < end; i += 4) {
        const bool vb  = (i + 2) < end;
        const int  ia  = i;
        const int  ib  = vb ? i + 2 : i;
        // issue all index loads up front (independent)
        const int rda = rd_arr[ia], rfa = rf_arr[ia];
        const int rdb = rd_arr[ib], rfb = rf_arr[ib];
        // two depth gathers + two feature-row gathers in flight per half-wave
        const float da = depth[rda];
        const float db = vb ? depth[rdb] : 0.f;
        const uint2 fa = featT[(size_t)rfa * (C_ / 4) + sl];
        const uint2 fb = featT[(size_t)rfb * (C_ / 4) + sl];
        a0 = fmaf(da, __uint_as_float(fa.x << 16),        a0);
        a1 = fmaf(da, __uint_as_float(fa.x & 0xffff0000u), a1);
        a2 = fmaf(da, __uint_as_float(fa.y << 16),        a2);
        a3 = fmaf(da, __uint_as_float(fa.y & 0xffff0000u), a3);
        a0 = fmaf(db, __uint_as_float(fb.x << 16),        a0);
        a1 = fmaf(db, __uint_as_float(fb.x & 0xffff0000u), a1);
        a2 = fmaf(db, __uint_as_float(fb.y << 16),        a2);
        a3 = fmaf(db, __uint_as_float(fb.y & 0xffff0000u), a3);
    }
    // fold the two half-wave partial sums (same channels, different points)
    a0 += __shfl_down(a0, 32);
    a1 += __shfl_down(a1, 32);
    a2 += __shfl_down(a2, 32);
    a3 += __shfl_down(a3, 32);

    if (half == 0) {
        if (COAL) {
            float4* o = (float4*)(dst + (size_t)cell * C_);
            o[sl] = make_float4(a0, a1, a2, a3);              // 512B coalesced
        } else {
            const int b  = cell >> 14;
            const int sp = cell & (SPAT_ - 1);
            float* o = dst + (size_t)b * ((size_t)C_ * SPAT_) + sp;
            o[(size_t)(4 * sl)     * SPAT_] = a0;
            o[(size_t)(4 * sl + 1) * SPAT_] = a1;
            o[(size_t)(4 * sl + 2) * SPAT_] = a2;
            o[(size_t)(4 * sl + 3) * SPAT_] = a3;
        }
    }
}

// ---------------------------------------------------------------------------
// cellbuf [B, SPAT, C] f32 -> out [B, C, SPAT] f32 (both sides coalesced)
// ---------------------------------------------------------------------------
__global__ __launch_bounds__(256) void transpose_out_k(const float* __restrict__ cellbuf,
                                                       float* __restrict__ out) {
    __shared__ float tile[32][33];
    const int b   = blockIdx.z;
    const int sp0 = blockIdx.x * 32;
    const int c0  = blockIdx.y * 32;
    const int x = threadIdx.x;
    const int y = threadIdx.y;

    const float* src = cellbuf + ((size_t)b * SPAT_ + sp0) * C_ + c0;
    #pragma unroll
    for (int yy = y; yy < 32; yy += 8)
        tile[yy][x] = src[(size_t)yy * C_ + x];
    __syncthreads();
    float* dst = out + ((size_t)b * C_ + c0) * SPAT_ + sp0;
    #pragma unroll
    for (int yy = y; yy < 32; yy += 8)
        dst[(size_t)yy * SPAT_ + x] = tile[x][yy];
}

// ---------------------------------------------------------------------------
// Fallback (ws too small): original-layout reads, scattered stores.
// ---------------------------------------------------------------------------
__global__ __launch_bounds__(256) void bevpool_fallback_k(const float* __restrict__ depth,
                                                          const float* __restrict__ feat,
                                                          const int* __restrict__ rd_arr,
                                                          const int* __restrict__ rf_arr,
                                                          const int* __restrict__ rb,
                                                          const int* __restrict__ istart,
                                                          const int* __restrict__ ilen,
                                                          float* __restrict__ out,
                                                          int n_intervals) {
    const int wave = (int)((blockIdx.x * blockDim.x + threadIdx.x) >> 6);
    const int lane = threadIdx.x & 63;
    if (wave >= n_intervals) return;
    const int start = istart[wave];
    const int len   = ilen[wave];
    const int cell  = rb[start];
    float ax = 0.f, ay = 0.f;
    const int end = start + len;
    for (int i = start; i < end; ++i) {
        const int rfi = rf_arr[i];
        const int bn  = rfi / HW_;
        const int hw  = rfi - bn * HW_;
        const float d = depth[rd_arr[i]];
        const float* frow = feat + (size_t)bn * (C_ * HW_) + hw;
        ax = fmaf(d, frow[(size_t)(2 * lane)     * HW_], ax);
        ay = fmaf(d, frow[(size_t)(2 * lane + 1) * HW_], ay);
    }
    const int b  = cell >> 14;
    const int sp = cell & (SPAT_ - 1);
    float* o = out + (size_t)b * ((size_t)C_ * SPAT_) + sp;
    o[(size_t)(2 * lane)     * SPAT_] = ax;
    o[(size_t)(2 * lane + 1) * SPAT_] = ay;
}

extern "C" void kernel_launch(void* const* d_in, const int* in_sizes, int n_in,
                              void* d_out, int out_size, void* d_ws, size_t ws_size,
                              hipStream_t stream) {
    const float* depth  = (const float*)d_in[0];
    const float* feat   = (const float*)d_in[1];
    const int*   rd     = (const int*)d_in[2];
    const int*   rf     = (const int*)d_in[3];
    const int*   rb     = (const int*)d_in[4];
    const int*   istart = (const int*)d_in[5];
    const int*   ilen   = (const int*)d_in[6];
    float*       out    = (float*)d_out;
    const int n_intervals = in_sizes[5];

    const size_t cellbuf_bytes = (size_t)CELLS_ * C_ * sizeof(float);          // 16.78 MB
    const size_t featT_bytes   = (size_t)BN_ * HW_ * C_ * sizeof(__hip_bfloat16); // 8.65 MB
    const int blocks = (n_intervals + 3) / 4;   // 4 waves per 256-thread block

    if (ws_size >= cellbuf_bytes + featT_bytes) {
        float*          cellbuf = (float*)d_ws;
        __hip_bfloat16* featT   = (__hip_bfloat16*)((char*)d_ws + cellbuf_bytes);
        hipMemsetAsync(cellbuf, 0, cellbuf_bytes, stream);   // empty cells -> 0
        {
            dim3 g(HW_ / 32, C_ / 32, BN_);
            dim3 b(32, 8);
            transpose_feat_bf16_k<<<g, b, 0, stream>>>(feat, featT);
        }
        bevpool_main_bf16_k<true><<<blocks, 256, 0, stream>>>(
            depth, (const uint2*)featT, rd, rf, rb, istart, ilen, cellbuf, n_intervals);
        {
            dim3 g(SPAT_ / 32, C_ / 32, 2);
            dim3 b(32, 8);
            transpose_out_k<<<g, b, 0, stream>>>(cellbuf, out);
        }
    } else if (ws_size >= featT_bytes) {
        __hip_bfloat16* featT = (__hip_bfloat16*)d_ws;
        hipMemsetAsync(out, 0, (size_t)out_size * sizeof(float), stream);
        {
            dim3 g(HW_ / 32, C_ / 32, BN_);
            dim3 b(32, 8);
            transpose_feat_bf16_k<<<g, b, 0, stream>>>(feat, featT);
        }
        bevpool_main_bf16_k<false><<<blocks, 256, 0, stream>>>(
            depth, (const uint2*)featT, rd, rf, rb, istart, ilen, out, n_intervals);
    } else {
        hipMemsetAsync(out, 0, (size_t)out_size * sizeof(float), stream);
        bevpool_fallback_k<<<blocks, 256, 0, stream>>>(
            depth, feat, rd, rf, rb, istart, ilen, out, n_intervals);
    }
}

// Round 4
// 75.319 us; speedup vs baseline: 2.0203x; 1.1351x over previous
//
#include <hip/hip_runtime.h>
#include <hip/hip_bf16.h>

// Problem constants (from reference):
// B=2, N=6, D=120, H=32, W=88, C=128, Z=1, HO=128, WO=128
#define HW_    2816
#define C_     128
#define BN_    12
#define SPAT_  16384
#define CELLS_ 32768

// ---------------------------------------------------------------------------
// feat [BN, C, HW] f32  ->  featT [BN, HW, C] bf16 (contiguous 256B per point)
// ---------------------------------------------------------------------------
__global__ __launch_bounds__(256) void transpose_feat_bf16_k(const float* __restrict__ feat,
                                                             __hip_bfloat16* __restrict__ featT) {
    __shared__ float tile[32][33];
    const int bn  = blockIdx.z;
    const int hw0 = blockIdx.x * 32;
    const int c0  = blockIdx.y * 32;
    const int x = threadIdx.x;   // 0..31
    const int y = threadIdx.y;   // 0..7

    const float* src = feat + ((size_t)bn * C_ + c0) * HW_ + hw0;
    #pragma unroll
    for (int yy = y; yy < 32; yy += 8)
        tile[yy][x] = src[(size_t)yy * HW_ + x];       // coalesced along hw
    __syncthreads();
    __hip_bfloat16* dst = featT + ((size_t)bn * HW_ + hw0) * C_ + c0;
    #pragma unroll
    for (int yy = y; yy < 32; yy += 8)
        dst[(size_t)yy * C_ + x] = __float2bfloat16(tile[x][yy]);  // coalesced along c
}

// ---------------------------------------------------------------------------
// Main: one wave per interval. 4 groups of 16 lanes; lane owns 8 channels
// (one uint4 = bf16x8; 16 lanes x 16B = full 256B feature row). Group g owns
// points i ≡ g (mod 4); hand-unrolled x4 (stride 16) -> 4 independent feature
// gathers + 4 depth gathers in flight per wave, tail via predicated d=0
// (round-2-proven pattern — no readlane, no LDS). Cross-group reduce via
// shfl_down(32)+shfl_down(16); group 0 stores 512B coalesced to cellbuf.
// ---------------------------------------------------------------------------
__global__ __launch_bounds__(256) void bevpool_main16_k(const float* __restrict__ depth,
                                                        const uint4* __restrict__ featT,
                                                        const int* __restrict__ rd_arr,
                                                        const int* __restrict__ rf_arr,
                                                        const int* __restrict__ rb,
                                                        const int* __restrict__ istart,
                                                        const int* __restrict__ ilen,
                                                        float* __restrict__ cellbuf,
                                                        int n_intervals) {
    const int wave = (int)((blockIdx.x * blockDim.x + threadIdx.x) >> 6);
    if (wave >= n_intervals) return;
    const int lane = threadIdx.x & 63;
    const int grp  = lane >> 4;        // 0..3: which point residue this group owns
    const int sl   = lane & 15;        // channel block: channels 8*sl .. 8*sl+7

    const int start = istart[wave];
    const int end   = start + ilen[wave];
    const int cell  = rb[start];

    float acc[8] = {0.f, 0.f, 0.f, 0.f, 0.f, 0.f, 0.f, 0.f};

#define FMA8(d, f)                                                   \
    acc[0] = fmaf(d, __uint_as_float((f).x << 16),         acc[0]);  \
    acc[1] = fmaf(d, __uint_as_float((f).x & 0xffff0000u), acc[1]);  \
    acc[2] = fmaf(d, __uint_as_float((f).y << 16),         acc[2]);  \
    acc[3] = fmaf(d, __uint_as_float((f).y & 0xffff0000u), acc[3]);  \
    acc[4] = fmaf(d, __uint_as_float((f).z << 16),         acc[4]);  \
    acc[5] = fmaf(d, __uint_as_float((f).z & 0xffff0000u), acc[5]);  \
    acc[6] = fmaf(d, __uint_as_float((f).w << 16),         acc[6]);  \
    acc[7] = fmaf(d, __uint_as_float((f).w & 0xffff0000u), acc[7]);

    for (int i = start + grp; i < end; i += 16) {
        const int i0 = i;
        const int i1 = (i + 4  < end) ? i + 4  : i0;   // clamp to valid address
        const int i2 = (i + 8  < end) ? i + 8  : i0;
        const int i3 = (i + 12 < end) ? i + 12 : i0;
        // all index loads issued up front (independent, group-broadcast)
        const int rd0 = rd_arr[i0], rf0 = rf_arr[i0];
        const int rd1 = rd_arr[i1], rf1 = rf_arr[i1];
        const int rd2 = rd_arr[i2], rf2 = rf_arr[i2];
        const int rd3 = rd_arr[i3], rf3 = rf_arr[i3];
        // 4 depth gathers in flight
        float d0 = depth[rd0];
        float d1 = depth[rd1];
        float d2 = depth[rd2];
        float d3 = depth[rd3];
        d1 = (i + 4  < end) ? d1 : 0.f;   // predicate AFTER load (mul-by-0 tail)
        d2 = (i + 8  < end) ? d2 : 0.f;
        d3 = (i + 12 < end) ? d3 : 0.f;
        // 4 feature-row gathers in flight (16 lanes x 16B = 256B per row)
        const uint4 f0 = featT[(size_t)rf0 * (C_ / 8) + sl];
        const uint4 f1 = featT[(size_t)rf1 * (C_ / 8) + sl];
        const uint4 f2 = featT[(size_t)rf2 * (C_ / 8) + sl];
        const uint4 f3 = featT[(size_t)rf3 * (C_ / 8) + sl];
        FMA8(d0, f0);
        FMA8(d1, f1);
        FMA8(d2, f2);
        FMA8(d3, f3);
    }
#undef FMA8

    // combine the 4 groups' partial sums (same channels, different points)
    #pragma unroll
    for (int c = 0; c < 8; ++c) {
        acc[c] += __shfl_down(acc[c], 32);
        acc[c] += __shfl_down(acc[c], 16);
    }

    if (grp == 0) {
        float4* o = (float4*)(cellbuf + (size_t)cell * C_ + sl * 8);
        o[0] = make_float4(acc[0], acc[1], acc[2], acc[3]);   // 512B coalesced
        o[1] = make_float4(acc[4], acc[5], acc[6], acc[7]);
    }
}

// ---------------------------------------------------------------------------
// cellbuf [B, SPAT, C] f32 -> out [B, C, SPAT] f32 (both sides coalesced)
// ---------------------------------------------------------------------------
__global__ __launch_bounds__(256) void transpose_out_k(const float* __restrict__ cellbuf,
                                                       float* __restrict__ out) {
    __shared__ float tile[32][33];
    const int b   = blockIdx.z;
    const int sp0 = blockIdx.x * 32;
    const int c0  = blockIdx.y * 32;
    const int x = threadIdx.x;
    const int y = threadIdx.y;

    const float* src = cellbuf + ((size_t)b * SPAT_ + sp0) * C_ + c0;
    #pragma unroll
    for (int yy = y; yy < 32; yy += 8)
        tile[yy][x] = src[(size_t)yy * C_ + x];
    __syncthreads();
    float* dst = out + ((size_t)b * C_ + c0) * SPAT_ + sp0;
    #pragma unroll
    for (int yy = y; yy < 32; yy += 8)
        dst[(size_t)yy * SPAT_ + x] = tile[x][yy];
}

// ---------------------------------------------------------------------------
// Fallback (ws too small): original-layout reads, scattered stores.
// ---------------------------------------------------------------------------
__global__ __launch_bounds__(256) void bevpool_fallback_k(const float* __restrict__ depth,
                                                          const float* __restrict__ feat,
                                                          const int* __restrict__ rd_arr,
                                                          const int* __restrict__ rf_arr,
                                                          const int* __restrict__ rb,
                                                          const int* __restrict__ istart,
                                                          const int* __restrict__ ilen,
                                                          float* __restrict__ out,
                                                          int n_intervals) {
    const int wave = (int)((blockIdx.x * blockDim.x + threadIdx.x) >> 6);
    const int lane = threadIdx.x & 63;
    if (wave >= n_intervals) return;
    const int start = istart[wave];
    const int len   = ilen[wave];
    const int cell  = rb[start];
    float ax = 0.f, ay = 0.f;
    const int end = start + len;
    for (int i = start; i < end; ++i) {
        const int rfi = rf_arr[i];
        const int bn  = rfi / HW_;
        const int hw  = rfi - bn * HW_;
        const float d = depth[rd_arr[i]];
        const float* frow = feat + (size_t)bn * (C_ * HW_) + hw;
        ax = fmaf(d, frow[(size_t)(2 * lane)     * HW_], ax);
        ay = fmaf(d, frow[(size_t)(2 * lane + 1) * HW_], ay);
    }
    const int b  = cell >> 14;
    const int sp = cell & (SPAT_ - 1);
    float* o = out + (size_t)b * ((size_t)C_ * SPAT_) + sp;
    o[(size_t)(2 * lane)     * SPAT_] = ax;
    o[(size_t)(2 * lane + 1) * SPAT_] = ay;
}

extern "C" void kernel_launch(void* const* d_in, const int* in_sizes, int n_in,
                              void* d_out, int out_size, void* d_ws, size_t ws_size,
                              hipStream_t stream) {
    const float* depth  = (const float*)d_in[0];
    const float* feat   = (const float*)d_in[1];
    const int*   rd     = (const int*)d_in[2];
    const int*   rf     = (const int*)d_in[3];
    const int*   rb     = (const int*)d_in[4];
    const int*   istart = (const int*)d_in[5];
    const int*   ilen   = (const int*)d_in[6];
    float*       out    = (float*)d_out;
    const int n_intervals = in_sizes[5];

    const size_t cellbuf_bytes = (size_t)CELLS_ * C_ * sizeof(float);             // 16.78 MB
    const size_t featT_bytes   = (size_t)BN_ * HW_ * C_ * sizeof(__hip_bfloat16); // 8.65 MB
    const int blocks = (n_intervals + 3) / 4;   // 4 waves per 256-thread block

    if (ws_size >= cellbuf_bytes + featT_bytes) {
        float*          cellbuf = (float*)d_ws;
        __hip_bfloat16* featT   = (__hip_bfloat16*)((char*)d_ws + cellbuf_bytes);
        hipMemsetAsync(cellbuf, 0, cellbuf_bytes, stream);   // empty cells -> 0
        {
            dim3 g(HW_ / 32, C_ / 32, BN_);
            dim3 b(32, 8);
            transpose_feat_bf16_k<<<g, b, 0, stream>>>(feat, featT);
        }
        bevpool_main16_k<<<blocks, 256, 0, stream>>>(
            depth, (const uint4*)featT, rd, rf, rb, istart, ilen,
            cellbuf, n_intervals);
        {
            dim3 g(SPAT_ / 32, C_ / 32, 2);
            dim3 b(32, 8);
            transpose_out_k<<<g, b, 0, stream>>>(cellbuf, out);
        }
    } else {
        hipMemsetAsync(out, 0, (size_t)out_size * sizeof(float), stream);
        bevpool_fallback_k<<<blocks, 256, 0, stream>>>(
            depth, feat, rd, rf, rb, istart, ilen, out, n_intervals);
    }
}